// Round 1
// baseline (371.418 us; speedup 1.0000x reference)
//
#include <hip/hip_runtime.h>
#include <hip/hip_bf16.h>
#include <stdint.h>

// Problem: B=16, S=2048, I=1024, H=1024  (all fp32 in/out)
// out[b,s,h] = tanh( sum_i x[b,s,i]*W_ih[h,i] + b_ih[h] + sum_k hx[b,k]*W_hh[h,k] + b_hh[h] )
// M = B*S = 32768, N = H = 1024, K = I = 1024.
//
// This version fuses the fp32->bf16 conversion of X into the GEMM's A-staging
// (reg-stage: global fp32 load -> v_cvt_pk_bf16_f32 -> ds_write_b128), removing
// the 207 MB standalone convert pass. W_ih (2 MB) is still pre-converted, fused
// into the hterm prep kernel. Block->tile mapping is XCD-corrected: each XCD
// owns a contiguous m-range with n innermost, so A-tiles are reused in that
// XCD's private L2 across all 8 n-tiles and B is L2-resident.

#define M_TOT 32768
#define N_TOT 1024
#define K_TOT 1024

typedef short short8 __attribute__((ext_vector_type(8)));   // 8 bf16 (4 VGPRs)
typedef float f32x4  __attribute__((ext_vector_type(4)));   // 4 fp32 acc

// ---- workspace layout (bytes) ----
// [0, 2097152)        W_bf  : 1048576 bf16
// [2097152, 2162688)  h_term: 16384 fp32
#define WS_WBF_OFF 0
#define WS_HT_OFF  2097152

__device__ __forceinline__ unsigned short f32_to_bf16_rne(float f) {
    union { float f; unsigned int u; } v; v.f = f;
    unsigned int u = v.u;
    unsigned int r = u + 0x7fffu + ((u >> 16) & 1u);
    return (unsigned short)(r >> 16);
}

// packed RNE f32->bf16: D[15:0]=bf16(lo), D[31:16]=bf16(hi)  (guide §5.5 T12 recipe)
__device__ __forceinline__ unsigned int cvt_pk_bf16(float lo, float hi) {
    unsigned int r;
    asm("v_cvt_pk_bf16_f32 %0, %1, %2" : "=v"(r) : "v"(lo), "v"(hi));
    return r;
}

__device__ __forceinline__ float fast_tanh(float z) {
    // tanh(z) = 1 - 2/(exp(2z)+1); __expf -> v_exp_f32. Saturates correctly at +-inf.
    float e = __expf(2.0f * z);
    return 1.0f - 2.0f / (e + 1.0f);
}

// ---------------- kernel 1: prep = h_term + W_ih fp32->bf16 ----------------
// blocks [0,4096): h_term[b,h] = hx[b,:].W_hh[h,:] + b_ih[h] + b_hh[h]  (1 wave each, 4/block)
// blocks [4096,4224): convert W_ih (131072 vec8 groups over 32768 threads, 4 iters)
__global__ void prep_kernel(const float* __restrict__ hx,
                            const float* __restrict__ whh,
                            const float* __restrict__ bih,
                            const float* __restrict__ bhh,
                            const float* __restrict__ wih,
                            float* __restrict__ ht,
                            unsigned short* __restrict__ wbf) {
    if (blockIdx.x < 4096) {
        int lane = threadIdx.x & 63;
        int w    = threadIdx.x >> 6;
        int wg   = blockIdx.x * 4 + w;        // 0..16383
        int b = wg >> 10, h = wg & 1023;
        const float* hr = hx  + (long long)b * 1024;
        const float* wr = whh + (long long)h * 1024;
        float s = 0.f;
#pragma unroll
        for (int p = 0; p < 4; ++p) {
            int idx = p * 256 + lane * 4;
            float4 a = *(const float4*)(hr + idx);
            float4 c = *(const float4*)(wr + idx);
            s += a.x * c.x + a.y * c.y + a.z * c.z + a.w * c.w;
        }
#pragma unroll
        for (int d = 32; d > 0; d >>= 1) s += __shfl_down(s, d, 64);
        if (lane == 0) ht[wg] = s + bih[h] + bhh[h];
    } else {
        int g = (blockIdx.x - 4096) * 256 + threadIdx.x;   // 0..32767
        for (int v = g; v < 131072; v += 32768) {
            long long base = (long long)v * 8;
            float4 a = *(const float4*)(wih + base);
            float4 b = *(const float4*)(wih + base + 4);
            union { unsigned short s[8]; uint4 u; } o;
            o.s[0] = f32_to_bf16_rne(a.x); o.s[1] = f32_to_bf16_rne(a.y);
            o.s[2] = f32_to_bf16_rne(a.z); o.s[3] = f32_to_bf16_rne(a.w);
            o.s[4] = f32_to_bf16_rne(b.x); o.s[5] = f32_to_bf16_rne(b.y);
            o.s[6] = f32_to_bf16_rne(b.z); o.s[7] = f32_to_bf16_rne(b.w);
            *(uint4*)(wbf + base) = o.u;
        }
    }
}

// ---------------- kernel 2: fused convert + bf16 MFMA GEMM + tanh epilogue ----------------
// 128x128 tile, BK=32, 256 threads = 4 waves in 2x2, each wave 64x64 (4x4 MFMA 16x16x32).
// A (X, fp32): reg-staged -> cvt_pk_bf16 -> ds_write_b128 with XOR chunk swizzle
//   chunk slot = (q + (row>>1)) & 3  (same swizzle as the fragment reads).
// B (W_ih, bf16): global_load_lds width=16 with the inverse swizzle pre-applied
//   to the per-lane global address (linear LDS dest).
#define GLDS16(gp, lp) \
    __builtin_amdgcn_global_load_lds((const __attribute__((address_space(1))) void*)(gp), \
                                     (__attribute__((address_space(3))) void*)(lp), 16, 0, 0)

__global__ __launch_bounds__(256) void gemm_tanh_kernel(
    const float* __restrict__ X,            // [32768,1024] fp32
    const unsigned short* __restrict__ Bm,  // [1024,1024]  bf16 (W_ih, row n is K-contiguous)
    const float* __restrict__ ht,           // [16,1024]
    float* __restrict__ out)                // [32768,1024] fp32
{
    __shared__ __align__(16) char lds[16384];   // A tile: [0,8192), B tile: [8192,16384)

    const int tid = threadIdx.x;
    const int w = tid >> 6, l = tid & 63;

    // XCD-corrected mapping: bid round-robins over 8 XCDs, so give XCD x the
    // contiguous work range [x*256, x*256+256) with n-tile innermost. A-tile
    // is then fetched once into that XCD's L2 and reused by all 8 n-tiles;
    // B (2 MB) is L2-resident per XCD.
    const int bid  = blockIdx.x;
    const int widx = (bid & 7) * 256 + (bid >> 3);
    const int tile_m = widx >> 3;      // 0..255
    const int tile_n = widx & 7;       // 0..7
    const int m0 = tile_m << 7, n0 = tile_n << 7;

    // ---- A staging (reg-staged fp32) ----
    // thread t: row = t>>1 (0..127), half = t&1 -> 16 contiguous K floats.
    // Chunks q0 = half*2, q1 = half*2+1 (8 K-elems each), written to swizzled
    // 16B slot (q + (row>>1)) & 3 of LDS row (64 B/row).
    const int rowA  = tid >> 1;
    const int halfA = tid & 1;
    const float* gA = X + (long long)(m0 + rowA) * K_TOT + halfA * 16;
    const int swzA = (rowA >> 1) & 3;
    char* lA0 = lds + rowA * 64 + (((halfA * 2 + 0 + swzA) & 3) << 4);
    char* lA1 = lds + rowA * 64 + (((halfA * 2 + 1 + swzA) & 3) << 4);

    // ---- B staging (global_load_lds, 2 instr per thread per K-iter) ----
    // wave w, instr j covers tile rows [(w*2+j)*16, +16); lane l -> row +(l>>2),
    // 16B slot (l&3). Slot s holds global chunk qg = (s - (row>>1)) & 3.
    const int r0 = (w * 2 + 0) * 16 + (l >> 2);
    const int r1 = (w * 2 + 1) * 16 + (l >> 2);
    const int slot = l & 3;
    const int qg0 = (slot - (r0 >> 1)) & 3;
    const int qg1 = (slot - (r1 >> 1)) & 3;
    const unsigned short* gB0 = Bm + (long long)(n0 + r0) * K_TOT + qg0 * 8;
    const unsigned short* gB1 = Bm + (long long)(n0 + r1) * K_TOT + qg1 * 8;
    char* ldsB0 = lds + 8192 + (w * 2 + 0) * 1024;
    char* ldsB1 = lds + 8192 + (w * 2 + 1) * 1024;

    // ---- fragment read offsets ----
    const int wm = w & 1, wn = w >> 1;       // 2x2 wave grid
    const int lm = l & 15, q = l >> 4;       // MFMA operand: row = lm, k-chunk = q
    int offA[4], offB[4];
#pragma unroll
    for (int t = 0; t < 4; ++t) {
        int rr = wm * 64 + t * 16 + lm;
        offA[t] = rr * 64 + (((q + (rr >> 1)) & 3) << 4);
        int nn = wn * 64 + t * 16 + lm;
        offB[t] = 8192 + nn * 64 + (((q + (nn >> 1)) & 3) << 4);
    }

    f32x4 acc[4][4];
#pragma unroll
    for (int i = 0; i < 4; ++i)
#pragma unroll
        for (int j = 0; j < 4; ++j)
            acc[i][j] = (f32x4){0.f, 0.f, 0.f, 0.f};

    // prologue: A fp32 for K-iter 0 into regs
    float4 a0 = *(const float4*)(gA + 0);
    float4 a1 = *(const float4*)(gA + 4);
    float4 a2 = *(const float4*)(gA + 8);
    float4 a3 = *(const float4*)(gA + 12);

    for (int k0 = 0; k0 < K_TOT; k0 += 32) {
        // convert current A regs -> bf16, write swizzled LDS chunks
        uint4 pk0, pk1;
        pk0.x = cvt_pk_bf16(a0.x, a0.y); pk0.y = cvt_pk_bf16(a0.z, a0.w);
        pk0.z = cvt_pk_bf16(a1.x, a1.y); pk0.w = cvt_pk_bf16(a1.z, a1.w);
        pk1.x = cvt_pk_bf16(a2.x, a2.y); pk1.y = cvt_pk_bf16(a2.z, a2.w);
        pk1.z = cvt_pk_bf16(a3.x, a3.y); pk1.w = cvt_pk_bf16(a3.z, a3.w);
        *(uint4*)lA0 = pk0;            // ds_write_b128 (even bank spread, 8-way min)
        *(uint4*)lA1 = pk1;
        GLDS16(gB0 + k0, ldsB0);
        GLDS16(gB1 + k0, ldsB1);
        __syncthreads();               // drains lgkm (A writes) + vm (B glds)

        short8 af[4], bf[4];
#pragma unroll
        for (int t = 0; t < 4; ++t) {
            af[t] = *(const short8*)(lds + offA[t]);
            bf[t] = *(const short8*)(lds + offB[t]);
        }

        // prefetch next K-iter's A fp32 under the MFMA cluster
        if (k0 + 32 < K_TOT) {
            const float* nA = gA + k0 + 32;
            a0 = *(const float4*)(nA + 0);
            a1 = *(const float4*)(nA + 4);
            a2 = *(const float4*)(nA + 8);
            a3 = *(const float4*)(nA + 12);
        }

#pragma unroll
        for (int mt = 0; mt < 4; ++mt)
#pragma unroll
            for (int nt = 0; nt < 4; ++nt)
                acc[mt][nt] = __builtin_amdgcn_mfma_f32_16x16x32_bf16(
                    af[mt], bf[nt], acc[mt][nt], 0, 0, 0);
        __syncthreads();
    }

    // ---- epilogue: out = tanh(acc + h_term[b, n]) ----
    // C/D layout: col = lane&15 (n), row = (lane>>4)*4 + reg (m).  [guide §3, m89-verified]
    const int b = tile_m >> 4;   // S=2048 -> 16 m-tiles per batch row; block is within one b
    float htv[4];
#pragma unroll
    for (int nt = 0; nt < 4; ++nt)
        htv[nt] = ht[b * 1024 + n0 + wn * 64 + nt * 16 + lm];

#pragma unroll
    for (int mt = 0; mt < 4; ++mt) {
#pragma unroll
        for (int nt = 0; nt < 4; ++nt) {
            int n = n0 + wn * 64 + nt * 16 + lm;
#pragma unroll
            for (int r = 0; r < 4; ++r) {
                int m = m0 + wm * 64 + mt * 16 + q * 4 + r;
                float z = acc[mt][nt][r] + htv[nt];
                out[(long long)m * N_TOT + n] = fast_tanh(z);
            }
        }
    }
}

extern "C" void kernel_launch(void* const* d_in, const int* in_sizes, int n_in,
                              void* d_out, int out_size, void* d_ws, size_t ws_size,
                              hipStream_t stream) {
    const float* x    = (const float*)d_in[0];   // [16,2048,1024]
    const float* hx   = (const float*)d_in[1];   // [16,1024]
    const float* wih  = (const float*)d_in[2];   // [1024,1024]
    const float* whh  = (const float*)d_in[3];   // [1024,1024]
    const float* bih  = (const float*)d_in[4];   // [1024]
    const float* bhh  = (const float*)d_in[5];   // [1024]
    float* out = (float*)d_out;

    unsigned short* wbf = (unsigned short*)((char*)d_ws + WS_WBF_OFF);
    float*          htp = (float*)((char*)d_ws + WS_HT_OFF);

    // prep: 4096 hterm blocks + 128 W-convert blocks
    prep_kernel<<<4224, 256, 0, stream>>>(hx, whh, bih, bhh, wih, htp, wbf);
    // fused convert+GEMM+tanh: 256 m-tiles x 8 n-tiles, XCD-remapped
    gemm_tanh_kernel<<<2048, 256, 0, stream>>>(x, wbf, htp, out);
}

// Round 2
// 361.665 us; speedup vs baseline: 1.0270x; 1.0270x over previous
//
#include <hip/hip_runtime.h>
#include <hip/hip_bf16.h>
#include <stdint.h>

// Problem: B=16, S=2048, I=1024, H=1024  (all fp32 in/out)
// out[b,s,h] = tanh( sum_i x[b,s,i]*W_ih[h,i] + b_ih[h] + sum_k hx[b,k]*W_hh[h,k] + b_hh[h] )
// M = B*S = 32768, N = H = 1024, K = I = 1024.
//
// v2: fused fp32->bf16 A-conversion (no standalone X convert pass) + XCD-corrected
// block mapping (kept from round 1: FETCH 265->90 MB) + NEW: double-buffered LDS,
// ONE raw s_barrier per K-iter with counted s_waitcnt vmcnt(4) (T3/T4 recipe).
// Round 1 lesson: __syncthreads drains vmcnt(0), exposing TWO full memory
// latencies per iter. Here A-reg loads get a full iteration of cover and B's
// global_load_lds is covered by the MFMA cluster; no vmcnt(0) in the main loop.

#define M_TOT 32768
#define N_TOT 1024
#define K_TOT 1024

typedef short short8 __attribute__((ext_vector_type(8)));   // 8 bf16 (4 VGPRs)
typedef float f32x4  __attribute__((ext_vector_type(4)));   // 4 fp32 acc

// ---- workspace layout (bytes) ----
// [0, 2097152)        W_bf  : 1048576 bf16
// [2097152, 2162688)  h_term: 16384 fp32
#define WS_WBF_OFF 0
#define WS_HT_OFF  2097152

__device__ __forceinline__ unsigned short f32_to_bf16_rne(float f) {
    union { float f; unsigned int u; } v; v.f = f;
    unsigned int u = v.u;
    unsigned int r = u + 0x7fffu + ((u >> 16) & 1u);
    return (unsigned short)(r >> 16);
}

// packed RNE f32->bf16: D[15:0]=bf16(lo), D[31:16]=bf16(hi)
__device__ __forceinline__ unsigned int cvt_pk_bf16(float lo, float hi) {
    unsigned int r;
    asm("v_cvt_pk_bf16_f32 %0, %1, %2" : "=v"(r) : "v"(lo), "v"(hi));
    return r;
}

__device__ __forceinline__ float fast_tanh(float z) {
    float e = __expf(2.0f * z);
    return 1.0f - 2.0f / (e + 1.0f);
}

// ---------------- kernel 1: prep = h_term + W_ih fp32->bf16 ----------------
__global__ void prep_kernel(const float* __restrict__ hx,
                            const float* __restrict__ whh,
                            const float* __restrict__ bih,
                            const float* __restrict__ bhh,
                            const float* __restrict__ wih,
                            float* __restrict__ ht,
                            unsigned short* __restrict__ wbf) {
    if (blockIdx.x < 4096) {
        int lane = threadIdx.x & 63;
        int w    = threadIdx.x >> 6;
        int wg   = blockIdx.x * 4 + w;        // 0..16383
        int b = wg >> 10, h = wg & 1023;
        const float* hr = hx  + (long long)b * 1024;
        const float* wr = whh + (long long)h * 1024;
        float s = 0.f;
#pragma unroll
        for (int p = 0; p < 4; ++p) {
            int idx = p * 256 + lane * 4;
            float4 a = *(const float4*)(hr + idx);
            float4 c = *(const float4*)(wr + idx);
            s += a.x * c.x + a.y * c.y + a.z * c.z + a.w * c.w;
        }
#pragma unroll
        for (int d = 32; d > 0; d >>= 1) s += __shfl_down(s, d, 64);
        if (lane == 0) ht[wg] = s + bih[h] + bhh[h];
    } else {
        int g = (blockIdx.x - 4096) * 256 + threadIdx.x;   // 0..32767
        for (int v = g; v < 131072; v += 32768) {
            long long base = (long long)v * 8;
            float4 a = *(const float4*)(wih + base);
            float4 b = *(const float4*)(wih + base + 4);
            union { unsigned short s[8]; uint4 u; } o;
            o.s[0] = f32_to_bf16_rne(a.x); o.s[1] = f32_to_bf16_rne(a.y);
            o.s[2] = f32_to_bf16_rne(a.z); o.s[3] = f32_to_bf16_rne(a.w);
            o.s[4] = f32_to_bf16_rne(b.x); o.s[5] = f32_to_bf16_rne(b.y);
            o.s[6] = f32_to_bf16_rne(b.z); o.s[7] = f32_to_bf16_rne(b.w);
            *(uint4*)(wbf + base) = o.u;
        }
    }
}

// ---------------- kernel 2: fused convert + bf16 MFMA GEMM + tanh ----------------
// 128x128 tile, BK=32, 256 threads = 4 waves in 2x2, each wave 64x64.
// LDS: double buffer, 16 KB each: buf p at [p*16384): A [0,8192) B [8192,16384).
#define GLDS16(gp, lp) \
    __builtin_amdgcn_global_load_lds((const __attribute__((address_space(1))) void*)(gp), \
                                     (__attribute__((address_space(3))) void*)(lp), 16, 0, 0)

// One K-iteration. T = iter index (for k offsets), P = compile-time buffer parity.
// CURx = reg set holding A(T+1) fp32 (consumed -> LDS this iter).
// NXTx = reg set to receive A(T+2) (issued this iter, waited next iter).
#define KITER(T, P, CUR0, CUR1, CUR2, CUR3, NXT0, NXT1, NXT2, NXT3)            \
  {                                                                            \
    /* 1. B(T+1) -> bufB[P^1]; safe: all waves passed barrier(T-1) */          \
    const int kb = (((T) + 1) & 31) * 32;                                      \
    GLDS16(gB0 + kb, ldsB0 + ((P) ^ 1) * 16384);                               \
    GLDS16(gB1 + kb, ldsB1 + ((P) ^ 1) * 16384);                               \
    __builtin_amdgcn_sched_barrier(0);  /* pin VMEM queue: B before A */       \
    /* 2. A(T+2) fp32 -> NXT regs (full-iter latency cover) */                 \
    const int ka = (((T) + 2) & 31) * 32;                                      \
    NXT0 = *(const float4*)(gA + ka + 0);                                      \
    NXT1 = *(const float4*)(gA + ka + 4);                                      \
    NXT2 = *(const float4*)(gA + ka + 8);                                      \
    NXT3 = *(const float4*)(gA + ka + 12);                                     \
    /* 3. fragments from buf[P] + 16 MFMA */                                   \
    {                                                                          \
      const char* lb = lds + (P) * 16384;                                      \
      short8 af[4], bfr[4];                                                    \
      _Pragma("unroll")                                                        \
      for (int t4 = 0; t4 < 4; ++t4) {                                         \
        af[t4]  = *(const short8*)(lb + offA[t4]);                             \
        bfr[t4] = *(const short8*)(lb + offB[t4]);                             \
      }                                                                        \
      _Pragma("unroll")                                                        \
      for (int mt = 0; mt < 4; ++mt)                                           \
        _Pragma("unroll")                                                      \
        for (int nt = 0; nt < 4; ++nt)                                         \
          acc[mt][nt] = __builtin_amdgcn_mfma_f32_16x16x32_bf16(               \
              af[mt], bfr[nt], acc[mt][nt], 0, 0, 0);                          \
    }                                                                          \
    /* 4. cvt A(T+1) -> ds_write bufA[P^1] (compiler waits CUR's vmcnt) */     \
    {                                                                          \
      uint4 pk0, pk1;                                                          \
      pk0.x = cvt_pk_bf16(CUR0.x, CUR0.y); pk0.y = cvt_pk_bf16(CUR0.z, CUR0.w);\
      pk0.z = cvt_pk_bf16(CUR1.x, CUR1.y); pk0.w = cvt_pk_bf16(CUR1.z, CUR1.w);\
      pk1.x = cvt_pk_bf16(CUR2.x, CUR2.y); pk1.y = cvt_pk_bf16(CUR2.z, CUR2.w);\
      pk1.z = cvt_pk_bf16(CUR3.x, CUR3.y); pk1.w = cvt_pk_bf16(CUR3.z, CUR3.w);\
      *(uint4*)(lA0 + ((P) ^ 1) * 16384) = pk0;                                \
      *(uint4*)(lA1 + ((P) ^ 1) * 16384) = pk1;                                \
    }                                                                          \
    /* 5. counted waits + ONE raw barrier. vmcnt(4): A(T+2)'s 4 loads may     \
       stay in flight; forces (older) B(T+1) GLDS complete. */                 \
    __builtin_amdgcn_sched_barrier(0);                                         \
    asm volatile("s_waitcnt vmcnt(4)" ::: "memory");                           \
    asm volatile("s_waitcnt lgkmcnt(0)" ::: "memory");                         \
    __builtin_amdgcn_s_barrier();                                              \
    __builtin_amdgcn_sched_barrier(0);                                         \
  }

__global__ __launch_bounds__(256) void gemm_tanh_kernel(
    const float* __restrict__ X,            // [32768,1024] fp32
    const unsigned short* __restrict__ Bm,  // [1024,1024]  bf16 (W_ih)
    const float* __restrict__ ht,           // [16,1024]
    float* __restrict__ out)                // [32768,1024] fp32
{
    __shared__ __align__(16) char lds[32768];

    const int tid = threadIdx.x;
    const int w = tid >> 6, l = tid & 63;

    // XCD-corrected mapping (round-1 verified: FETCH 265->90 MB): XCD x owns
    // contiguous m-range, n-tile innermost -> A-panel L2-resident per XCD.
    const int bid  = blockIdx.x;
    const int widx = (bid & 7) * 256 + (bid >> 3);
    const int tile_m = widx >> 3;      // 0..255
    const int tile_n = widx & 7;       // 0..7
    const int m0 = tile_m << 7, n0 = tile_n << 7;

    // ---- A staging (reg-staged fp32 -> cvt -> ds_write, XOR chunk swizzle) ----
    const int rowA  = tid >> 1;
    const int halfA = tid & 1;
    const float* gA = X + (long long)(m0 + rowA) * K_TOT + halfA * 16;
    const int swzA = (rowA >> 1) & 3;
    char* lA0 = lds + rowA * 64 + (((halfA * 2 + 0 + swzA) & 3) << 4);
    char* lA1 = lds + rowA * 64 + (((halfA * 2 + 1 + swzA) & 3) << 4);

    // ---- B staging (global_load_lds, inverse swizzle on global addr) ----
    const int r0 = (w * 2 + 0) * 16 + (l >> 2);
    const int r1 = (w * 2 + 1) * 16 + (l >> 2);
    const int slot = l & 3;
    const int qg0 = (slot - (r0 >> 1)) & 3;
    const int qg1 = (slot - (r1 >> 1)) & 3;
    const unsigned short* gB0 = Bm + (long long)(n0 + r0) * K_TOT + qg0 * 8;
    const unsigned short* gB1 = Bm + (long long)(n0 + r1) * K_TOT + qg1 * 8;
    char* ldsB0 = lds + 8192 + (w * 2 + 0) * 1024;
    char* ldsB1 = lds + 8192 + (w * 2 + 1) * 1024;

    // ---- fragment read offsets (within one 16 KB buffer) ----
    const int wm = w & 1, wn = w >> 1;
    const int lm = l & 15, q = l >> 4;
    int offA[4], offB[4];
#pragma unroll
    for (int t = 0; t < 4; ++t) {
        int rr = wm * 64 + t * 16 + lm;
        offA[t] = rr * 64 + (((q + (rr >> 1)) & 3) << 4);
        int nn = wn * 64 + t * 16 + lm;
        offB[t] = 8192 + nn * 64 + (((q + (nn >> 1)) & 3) << 4);
    }

    f32x4 acc[4][4];
#pragma unroll
    for (int i = 0; i < 4; ++i)
#pragma unroll
        for (int j = 0; j < 4; ++j)
            acc[i][j] = (f32x4){0.f, 0.f, 0.f, 0.f};

    // Two named A-register sets (rule #20: no runtime-indexed reg arrays).
    float4 s0_0, s0_1, s0_2, s0_3;   // even tiles
    float4 s1_0, s1_1, s1_2, s1_3;   // odd tiles

    // ---- prologue: establish invariant {buf0 = tile 0 ready; A(1) in flight} ----
    s0_0 = *(const float4*)(gA + 0);
    s0_1 = *(const float4*)(gA + 4);
    s0_2 = *(const float4*)(gA + 8);
    s0_3 = *(const float4*)(gA + 12);
    GLDS16(gB0, ldsB0);
    GLDS16(gB1, ldsB1);
    __builtin_amdgcn_sched_barrier(0);
    {
        uint4 pk0, pk1;
        pk0.x = cvt_pk_bf16(s0_0.x, s0_0.y); pk0.y = cvt_pk_bf16(s0_0.z, s0_0.w);
        pk0.z = cvt_pk_bf16(s0_1.x, s0_1.y); pk0.w = cvt_pk_bf16(s0_1.z, s0_1.w);
        pk1.x = cvt_pk_bf16(s0_2.x, s0_2.y); pk1.y = cvt_pk_bf16(s0_2.z, s0_2.w);
        pk1.z = cvt_pk_bf16(s0_3.x, s0_3.y); pk1.w = cvt_pk_bf16(s0_3.z, s0_3.w);
        *(uint4*)lA0 = pk0;
        *(uint4*)lA1 = pk1;
    }
    s1_0 = *(const float4*)(gA + 32 + 0);
    s1_1 = *(const float4*)(gA + 32 + 4);
    s1_2 = *(const float4*)(gA + 32 + 8);
    s1_3 = *(const float4*)(gA + 32 + 12);
    __builtin_amdgcn_sched_barrier(0);
    asm volatile("s_waitcnt vmcnt(4)" ::: "memory");   // B(0) done; A(1) in flight
    asm volatile("s_waitcnt lgkmcnt(0)" ::: "memory");
    __builtin_amdgcn_s_barrier();
    __builtin_amdgcn_sched_barrier(0);

    // ---- main loop: 32 K-iters, unrolled x2 for compile-time parity ----
    for (int tt = 0; tt < 32; tt += 2) {
        KITER(tt,     0, s1_0, s1_1, s1_2, s1_3, s0_0, s0_1, s0_2, s0_3);
        KITER(tt + 1, 1, s0_0, s0_1, s0_2, s0_3, s1_0, s1_1, s1_2, s1_3);
    }
    // drain tail wrap-loads so no GLDS lands in LDS after endpgm
    asm volatile("s_waitcnt vmcnt(0)" ::: "memory");

    // ---- epilogue: out = tanh(acc + h_term[b, n]) ----
    // C/D layout: col = lane&15 (n), row = (lane>>4)*4 + reg (m).
    const int b = tile_m >> 4;
    float htv[4];
#pragma unroll
    for (int nt = 0; nt < 4; ++nt)
        htv[nt] = ht[b * 1024 + n0 + wn * 64 + nt * 16 + lm];

#pragma unroll
    for (int mt = 0; mt < 4; ++mt) {
#pragma unroll
        for (int nt = 0; nt < 4; ++nt) {
            int n = n0 + wn * 64 + nt * 16 + lm;
#pragma unroll
            for (int r = 0; r < 4; ++r) {
                int m = m0 + wm * 64 + mt * 16 + q * 4 + r;
                float z = acc[mt][nt][r] + htv[nt];
                out[(long long)m * N_TOT + n] = fast_tanh(z);
            }
        }
    }
}

extern "C" void kernel_launch(void* const* d_in, const int* in_sizes, int n_in,
                              void* d_out, int out_size, void* d_ws, size_t ws_size,
                              hipStream_t stream) {
    const float* x    = (const float*)d_in[0];   // [16,2048,1024]
    const float* hx   = (const float*)d_in[1];   // [16,1024]
    const float* wih  = (const float*)d_in[2];   // [1024,1024]
    const float* whh  = (const float*)d_in[3];   // [1024,1024]
    const float* bih  = (const float*)d_in[4];   // [1024]
    const float* bhh  = (const float*)d_in[5];   // [1024]
    float* out = (float*)d_out;

    unsigned short* wbf = (unsigned short*)((char*)d_ws + WS_WBF_OFF);
    float*          htp = (float*)((char*)d_ws + WS_HT_OFF);

    prep_kernel<<<4224, 256, 0, stream>>>(hx, whh, bih, bhh, wih, htp, wbf);
    gemm_tanh_kernel<<<2048, 256, 0, stream>>>(x, wbf, htp, out);
}